// Round 10
// baseline (1230.062 us; speedup 1.0000x reference)
//
#include <hip/hip_runtime.h>
#include <hip/hip_bf16.h>
#include <stdint.h>

#define L 1024
#define D 1024
#define NLAYER 4
#define NSTATE 16
#define DI 2048
#define DTR 64
#define KCONV 4
#define XD 96      // DTR + 2*NSTATE
#define KSPLIT 8   // x_proj split-K
#define OSPLIT 4   // out_proj split-K
#define BK 32
#define DIST 4     // GEMM prefetch depth (iterations)
#define SCAND 32   // scan: channels per block
#define TT 64      // scan: timesteps per LDS tile

typedef __attribute__((ext_vector_type(8))) short short8;
typedef __attribute__((ext_vector_type(4))) float floatx4;

__device__ __forceinline__ float siluf(float x) { return x / (1.f + __expf(-x)); }

__device__ __forceinline__ unsigned short f2bf(float x) {
    __hip_bfloat16 b = __float2bfloat16(x);
    return *reinterpret_cast<unsigned short*>(&b);
}

__device__ __forceinline__ short8 pack8(floatx4 a, floatx4 b) {
    short8 o;
    o[0] = (short)f2bf(a.x); o[1] = (short)f2bf(a.y);
    o[2] = (short)f2bf(a.z); o[3] = (short)f2bf(a.w);
    o[4] = (short)f2bf(b.x); o[5] = (short)f2bf(b.y);
    o[6] = (short)f2bf(b.z); o[7] = (short)f2bf(b.w);
    return o;
}

// Barrier that does NOT drain vmcnt: deep global-load prefetches stay in flight.
#define BARRIER_NODRAIN() asm volatile("s_waitcnt lgkmcnt(0)\n\ts_barrier" ::: "memory")

// ---------------- RMSNorm (layer 0 input) -> bf16 ----------------
__global__ __launch_bounds__(256) void rmsnorm_kernel(const float* __restrict__ x,
                                                      const float* __restrict__ w,
                                                      __hip_bfloat16* __restrict__ out) {
    int row = blockIdx.x;
    const float* xr = x + (size_t)row * D;
    float v[4];
    float s = 0.f;
#pragma unroll
    for (int i = 0; i < 4; ++i) {
        v[i] = xr[threadIdx.x + i * 256];
        s += v[i] * v[i];
    }
#pragma unroll
    for (int off = 32; off > 0; off >>= 1) s += __shfl_xor(s, off, 64);
    __shared__ float red[4];
    int wave = threadIdx.x >> 6;
    if ((threadIdx.x & 63) == 0) red[wave] = s;
    __syncthreads();
    float inv = rsqrtf((red[0] + red[1] + red[2] + red[3]) * (1.f / D) + 1e-5f);
#pragma unroll
    for (int i = 0; i < 4; ++i) {
        int c = threadIdx.x + i * 256;
        out[(size_t)row * D + c] = __float2bfloat16(v[i] * inv * w[c]);
    }
}

// ---------------- pipelined GEMM (128x64 tile): C[M,N] = A[M,K] * B[N,K]^T ----------------
// A bf16, B fp32 (converted to bf16 during staging). EPI: 0 plain; 1 softplus(c + bias[n]).
template <int EPI, int ITERS>
__global__ __launch_bounds__(256, 2) void gemm_pipe(
    const __hip_bfloat16* __restrict__ A, int lda,
    const float* __restrict__ Bw, int ldb, int Brows,
    float* __restrict__ C, int ldc, int Nvalid,
    long zstride, const float* __restrict__ bias) {
    __shared__ __align__(16) __hip_bfloat16 As[2][128 * BK];
    __shared__ __align__(16) __hip_bfloat16 Bs[2][64 * BK];
    int tid = threadIdx.x;
    int wave = tid >> 6, lane = tid & 63;

    int gxy = gridDim.x * gridDim.y;
    int total = gxy * gridDim.z;
    int flat = (blockIdx.z * gridDim.y + blockIdx.y) * gridDim.x + blockIdx.x;
    int bm, bn, bz;
    if ((total & 7) == 0) {
        int lid = (flat & 7) * (total >> 3) + (flat >> 3);
        bz = lid / gxy;
        int rem = lid - bz * gxy;
        bn = rem / gridDim.y;
        bm = rem - bn * gridDim.y;
    } else {
        bm = blockIdx.y; bn = blockIdx.x; bz = blockIdx.z;
    }

    int m0 = bm * 128, n0 = bn * 64;
    int k_base = bz * (ITERS * BK);
    C += (long)bz * zstride;
    int wr = wave >> 1, wc = wave & 1;
    int srow = lane >> 2, scol = (lane & 3) * 8;
    int q = lane >> 4, r = lane & 15;

    floatx4 acc[4][2] = {};

    const __hip_bfloat16* gA0 = A + (long)(m0 + wave * 32 + srow) * lda + scol + k_base;
    const __hip_bfloat16* gA1 = gA0 + (long)16 * lda;
    int bnrow = n0 + wave * 16 + srow;
    const float* gB = Bw + (long)bnrow * ldb + scol + k_base;
    bool bok = bnrow < Brows;

    short8 qa0[DIST], qa1[DIST];
    floatx4 qb0[DIST] = {}, qb1[DIST] = {};

    auto ld = [&](int j) {
        int k0 = j * BK;
        int s = j & (DIST - 1);
        qa0[s] = *(const short8*)(gA0 + k0);
        qa1[s] = *(const short8*)(gA1 + k0);
        if (bok) {
            qb0[s] = *(const floatx4*)(gB + k0);
            qb1[s] = *(const floatx4*)(gB + k0 + 4);
        }
    };
    auto wrstage = [&](int j) {
        int p = j & 1, s = j & (DIST - 1);
        *(short8*)(&As[p][(wave * 32 + srow) * BK + scol]) = qa0[s];
        *(short8*)(&As[p][(wave * 32 + 16 + srow) * BK + scol]) = qa1[s];
        *(short8*)(&Bs[p][(wave * 16 + srow) * BK + scol]) = pack8(qb0[s], qb1[s]);
    };

#pragma unroll
    for (int j = 0; j < DIST; ++j)
        if (j < ITERS) ld(j);
    wrstage(0);

#pragma unroll
    for (int k = 0; k < ITERS; ++k) {
        BARRIER_NODRAIN();
        if (k + DIST < ITERS) ld(k + DIST);
        if (k + 1 < ITERS) wrstage(k + 1);
        const short* Ap = (const short*)As[k & 1];
        const short* Bp = (const short*)Bs[k & 1];
        short8 af[4], bfr[2];
#pragma unroll
        for (int i = 0; i < 4; ++i)
            af[i] = *(const short8*)(Ap + (wr * 64 + i * 16 + r) * BK + q * 8);
#pragma unroll
        for (int j = 0; j < 2; ++j)
            bfr[j] = *(const short8*)(Bp + (wc * 32 + j * 16 + r) * BK + q * 8);
#pragma unroll
        for (int i = 0; i < 4; ++i)
#pragma unroll
            for (int j = 0; j < 2; ++j)
                acc[i][j] = __builtin_amdgcn_mfma_f32_16x16x32_bf16(af[i], bfr[j], acc[i][j], 0, 0, 0);
    }

#pragma unroll
    for (int i = 0; i < 4; ++i) {
        int mrow = m0 + wr * 64 + i * 16 + q * 4;
#pragma unroll
        for (int j = 0; j < 2; ++j) {
            int ncol = n0 + wc * 32 + j * 16 + r;
            if (ncol < Nvalid) {
#pragma unroll
                for (int rr = 0; rr < 4; ++rr) {
                    float v = acc[i][j][rr];
                    int m = mrow + rr;
                    if (EPI == 1) {
                        v += bias[ncol];
                        v = v > 20.f ? v : log1pf(__expf(v));
                    }
                    C[(long)m * ldc + ncol] = v;
                }
            }
        }
    }
}

// ---------------- 128x128-tile GEMM, per-wave 64x64 ----------------
template <int ITERS>
__global__ __launch_bounds__(256, 1) void gemm128(
    const __hip_bfloat16* __restrict__ A, int lda,
    const float* __restrict__ Bw, int ldb, int Brows,
    float* __restrict__ C, int ldc, long zstride) {
    __shared__ __align__(16) __hip_bfloat16 As[2][128 * BK];
    __shared__ __align__(16) __hip_bfloat16 Bs[2][128 * BK];
    int tid = threadIdx.x;
    int wave = tid >> 6, lane = tid & 63;

    int gxy = gridDim.x * gridDim.y;
    int total = gxy * gridDim.z;
    int flat = (blockIdx.z * gridDim.y + blockIdx.y) * gridDim.x + blockIdx.x;
    int bm, bn, bz;
    if ((total & 7) == 0) {
        int lid = (flat & 7) * (total >> 3) + (flat >> 3);
        bz = lid / gxy;
        int rem = lid - bz * gxy;
        bn = rem / gridDim.y;
        bm = rem - bn * gridDim.y;
    } else {
        bm = blockIdx.y; bn = blockIdx.x; bz = blockIdx.z;
    }

    int m0 = bm * 128, n0 = bn * 128;
    int k_base = bz * (ITERS * BK);
    C += (long)bz * zstride;
    int wr = wave >> 1, wc = wave & 1;
    int srow = lane >> 2, scol = (lane & 3) * 8;
    int q = lane >> 4, r = lane & 15;

    floatx4 acc[4][4] = {};

    const __hip_bfloat16* gA0 = A + (long)(m0 + wave * 32 + srow) * lda + scol + k_base;
    const __hip_bfloat16* gA1 = gA0 + (long)16 * lda;
    int bn0 = n0 + wave * 32 + srow;
    const float* gB0 = Bw + (long)bn0 * ldb + scol + k_base;
    const float* gB1 = gB0 + (long)16 * ldb;
    bool bok0 = bn0 < Brows, bok1 = (bn0 + 16) < Brows;

    short8 qa0[DIST], qa1[DIST];
    floatx4 qb0[DIST] = {}, qb1[DIST] = {}, qb2[DIST] = {}, qb3[DIST] = {};

    auto ld = [&](int j) {
        int k0 = j * BK;
        int s = j & (DIST - 1);
        qa0[s] = *(const short8*)(gA0 + k0);
        qa1[s] = *(const short8*)(gA1 + k0);
        if (bok0) {
            qb0[s] = *(const floatx4*)(gB0 + k0);
            qb1[s] = *(const floatx4*)(gB0 + k0 + 4);
        }
        if (bok1) {
            qb2[s] = *(const floatx4*)(gB1 + k0);
            qb3[s] = *(const floatx4*)(gB1 + k0 + 4);
        }
    };
    auto wrstage = [&](int j) {
        int p = j & 1, s = j & (DIST - 1);
        *(short8*)(&As[p][(wave * 32 + srow) * BK + scol]) = qa0[s];
        *(short8*)(&As[p][(wave * 32 + 16 + srow) * BK + scol]) = qa1[s];
        *(short8*)(&Bs[p][(wave * 32 + srow) * BK + scol]) = pack8(qb0[s], qb1[s]);
        *(short8*)(&Bs[p][(wave * 32 + 16 + srow) * BK + scol]) = pack8(qb2[s], qb3[s]);
    };

#pragma unroll
    for (int j = 0; j < DIST; ++j)
        if (j < ITERS) ld(j);
    wrstage(0);

#pragma unroll
    for (int k = 0; k < ITERS; ++k) {
        BARRIER_NODRAIN();
        if (k + DIST < ITERS) ld(k + DIST);
        if (k + 1 < ITERS) wrstage(k + 1);
        const short* Ap = (const short*)As[k & 1];
        const short* Bp = (const short*)Bs[k & 1];
        short8 af[4], bfr[4];
#pragma unroll
        for (int i = 0; i < 4; ++i)
            af[i] = *(const short8*)(Ap + (wr * 64 + i * 16 + r) * BK + q * 8);
#pragma unroll
        for (int j = 0; j < 4; ++j)
            bfr[j] = *(const short8*)(Bp + (wc * 64 + j * 16 + r) * BK + q * 8);
#pragma unroll
        for (int i = 0; i < 4; ++i)
#pragma unroll
            for (int j = 0; j < 4; ++j)
                acc[i][j] = __builtin_amdgcn_mfma_f32_16x16x32_bf16(af[i], bfr[j], acc[i][j], 0, 0, 0);
    }

#pragma unroll
    for (int i = 0; i < 4; ++i) {
        int mrow = m0 + wr * 64 + i * 16 + q * 4;
#pragma unroll
        for (int j = 0; j < 4; ++j) {
            int ncol = n0 + wc * 64 + j * 16 + r;
#pragma unroll
            for (int rr = 0; rr < 4; ++rr)
                C[(long)(mrow + rr) * ldc + ncol] = acc[i][j][rr];
        }
    }
}

// ---------------- split-K reduce + residual (+fused RMSNorm for next layer) ----------------
template <int NPART, bool NORM>
__global__ __launch_bounds__(256) void reduce_kernel(const float* __restrict__ part2,
                                                     const float* __restrict__ xin,
                                                     const float* __restrict__ nw,
                                                     float* __restrict__ out,
                                                     __hip_bfloat16* __restrict__ xn) {
    int row = blockIdx.x;
    const float* xr = xin + (size_t)row * D;
    float v[4];
    float ss = 0.f;
#pragma unroll
    for (int i = 0; i < 4; ++i) {
        int c = threadIdx.x + i * 256;
        float s = xr[c];
#pragma unroll
        for (int p = 0; p < NPART; ++p)
            s += part2[(size_t)p * L * D + (size_t)row * D + c];
        v[i] = s;
        out[(size_t)row * D + c] = s;
        ss += s * s;
    }
    if (NORM) {
#pragma unroll
        for (int off = 32; off > 0; off >>= 1) ss += __shfl_xor(ss, off, 64);
        __shared__ float red[4];
        int wave = threadIdx.x >> 6;
        if ((threadIdx.x & 63) == 0) red[wave] = ss;
        __syncthreads();
        float inv = rsqrtf((red[0] + red[1] + red[2] + red[3]) * (1.f / D) + 1e-5f);
#pragma unroll
        for (int i = 0; i < 4; ++i) {
            int c = threadIdx.x + i * 256;
            xn[(size_t)row * D + c] = __float2bfloat16(v[i] * inv * nw[c]);
        }
    }
}

// ---------------- causal depthwise conv + bias + SiLU -> bf16 ----------------
__global__ __launch_bounds__(256) void conv_silu_kernel(const float* __restrict__ xz,
                                                        const float* __restrict__ cw,
                                                        const float* __restrict__ cb,
                                                        __hip_bfloat16* __restrict__ u) {
    int idx = blockIdx.x * 256 + threadIdx.x;  // t*DI + d
    int d = idx & (DI - 1);
    int t = idx >> 11;
    float acc = cb[d];
#pragma unroll
    for (int k = 0; k < KCONV; ++k) {
        int tk = t - (KCONV - 1) + k;
        if (tk >= 0) acc += xz[(size_t)tk * (2 * DI) + d] * cw[d * KCONV + k];
    }
    u[idx] = __float2bfloat16(siluf(acc));
}

// ---------------- x_proj partial reduce: part[8][L][96] -> xdbl_bf[L][64] + xdblBC[L][32] ----------------
__global__ __launch_bounds__(256) void xred_kernel(const float* __restrict__ part,
                                                   __hip_bfloat16* __restrict__ xdbl_bf,
                                                   float* __restrict__ xdblBC) {
    int i = blockIdx.x * 256 + threadIdx.x;  // < L*96
    int t = i / XD, col = i - t * XD;
    float s = 0.f;
#pragma unroll
    for (int sp = 0; sp < KSPLIT; ++sp) s += part[(size_t)sp * L * XD + i];
    if (col < DTR) xdbl_bf[(size_t)t * DTR + col] = __float2bfloat16(s);
    else xdblBC[(size_t)t * 32 + (col - DTR)] = s;
}

// ---------------- single-dispatch selective scan ----------------
// 64 blocks x 256 threads. Block owns SCAND=32 channels, scans all L serially.
// Thread = (dlocal, ng): dlocal = tid>>3 in [0,32), ng = tid&7; states n = {2ng, 2ng+1}.
// y[t][d] = sum_n h[n]*C[t][n] reduced over the 8 ng-lanes via 3x shfl_xor.
// No cross-block dependency at all (replaces scanA+scanB+scanC: -2 dispatch gaps).
// Double-buffered LDS tiles (TT=64 timesteps) hide the streaming loads.
__global__ __launch_bounds__(256) void scan1_kernel(
    const float* __restrict__ delta, const __hip_bfloat16* __restrict__ u,
    const float* __restrict__ xdblBC, const float* __restrict__ Alog,
    const float* __restrict__ xz, const float* __restrict__ Dskip,
    __hip_bfloat16* __restrict__ yg) {
    const int d0 = blockIdx.x * SCAND;
    const int tid = threadIdx.x;
    const int dl_ = tid >> 3;        // 0..31  (channel within block)
    const int ng = tid & 7;          // 0..7   (state pair group)
    const int d = d0 + dl_;
    const int n0 = ng * 2;

    __shared__ __align__(16) float dsl[2][TT * SCAND];
    __shared__ __align__(16) float usl[2][TT * SCAND];
    __shared__ __align__(16) float zsl[2][TT * SCAND];
    __shared__ __align__(16) float bcs[2][TT * 32];
    __shared__ __align__(16) float ysl[TT * SCAND];
    __shared__ float dskL[SCAND];

    if (tid < SCAND) dskL[tid] = Dskip[d0 + tid];

    float av0 = -__expf(Alog[(size_t)d * NSTATE + n0]);
    float av1 = -__expf(Alog[(size_t)d * NSTATE + n0 + 1]);
    float h0 = 0.f, h1 = 0.f;

    auto stage = [&](int b, int tile) {
        int T0 = tile * TT;
#pragma unroll
        for (int i = 0; i < (TT * SCAND) / 256; ++i) {   // 8 iters; rows of 32 floats = 128B
            int idx = i * 256 + tid;
            int tt = idx >> 5, col = idx & 31;
            int t = T0 + tt;
            dsl[b][idx] = delta[(size_t)t * DI + d0 + col];
            usl[b][idx] = __bfloat162float(u[(size_t)t * DI + d0 + col]);
            zsl[b][idx] = xz[(size_t)t * (2 * DI) + DI + d0 + col];
            bcs[b][idx] = xdblBC[(size_t)t * 32 + col];
        }
    };

    stage(0, 0);
    for (int tile = 0; tile < L / TT; ++tile) {
        int b = tile & 1;
        __syncthreads();                           // buf b staged; ysl free
        if (tile + 1 < L / TT) stage(b ^ 1, tile + 1);
#pragma unroll 4
        for (int tt = 0; tt < TT; ++tt) {
            float dlv = dsl[b][tt * SCAND + dl_];  // 8-dup broadcast reads
            float uu  = usl[b][tt * SCAND + dl_];
            float du  = dlv * uu;
            float bb0 = bcs[b][tt * 32 + n0];
            float bb1 = bcs[b][tt * 32 + n0 + 1];
            float cc0 = bcs[b][tt * 32 + 16 + n0];
            float cc1 = bcs[b][tt * 32 + 16 + n0 + 1];
            float a0 = __expf(dlv * av0);
            float a1 = __expf(dlv * av1);
            h0 = a0 * h0 + du * bb0;
            h1 = a1 * h1 + du * bb1;
            float y = h0 * cc0 + h1 * cc1;
            y += __shfl_xor(y, 1);                 // sum over 8 ng-lanes (group-aligned)
            y += __shfl_xor(y, 2);
            y += __shfl_xor(y, 4);
            if (ng == 0) ysl[tt * SCAND + dl_] = y;
        }
        __syncthreads();                           // ysl + next-tile stage complete
        int T0 = tile * TT;
#pragma unroll
        for (int i = 0; i < (TT * SCAND) / 256; ++i) {
            int idx = i * 256 + tid;
            int tt = idx >> 5, col = idx & 31;
            int t = T0 + tt;
            float y = ysl[idx];
            float uu = usl[b][idx];
            float z = zsl[b][idx];
            yg[(size_t)t * DI + d0 + col] =
                __float2bfloat16((y + uu * dskL[col]) * siluf(z));
        }
    }
}

// ---------------- host orchestration ----------------
extern "C" void kernel_launch(void* const* d_in, const int* in_sizes, int n_in,
                              void* d_out, int out_size, void* d_ws, size_t ws_size,
                              hipStream_t stream) {
    const float* x      = (const float*)d_in[0];
    const float* norm_w = (const float*)d_in[1];
    const float* in_w   = (const float*)d_in[2];
    const float* conv_w = (const float*)d_in[3];
    const float* conv_b = (const float*)d_in[4];
    const float* xproj_w= (const float*)d_in[5];
    const float* dt_w   = (const float*)d_in[6];
    const float* dt_b   = (const float*)d_in[7];
    const float* A_log  = (const float*)d_in[8];
    const float* D_skip = (const float*)d_in[9];
    const float* out_w  = (const float*)d_in[10];
    float* out = (float*)d_out;

    uint8_t* wp = (uint8_t*)d_ws;
    auto alloc = [&](size_t bytes) {
        uint8_t* p = wp;
        wp += (bytes + 255) & ~(size_t)255;
        return p;
    };
    __hip_bfloat16* xn_bf   = (__hip_bfloat16*)alloc((size_t)L * D * 2);
    float*          xz      = (float*)alloc((size_t)L * 2 * DI * 4);
    __hip_bfloat16* u_bf    = (__hip_bfloat16*)alloc((size_t)L * DI * 2);
    float*          part    = (float*)alloc((size_t)KSPLIT * L * XD * 4);
    __hip_bfloat16* xdbl_bf = (__hip_bfloat16*)alloc((size_t)L * DTR * 2);
    float*          xdblBC  = (float*)alloc((size_t)L * 32 * 4);
    float*          delta   = (float*)alloc((size_t)L * DI * 4);
    __hip_bfloat16* yg_bf   = (__hip_bfloat16*)alloc((size_t)L * DI * 2);
    float*          part2   = (float*)alloc((size_t)OSPLIT * L * D * 4);

    rmsnorm_kernel<<<L, 256, 0, stream>>>(x, norm_w, xn_bf);

    for (int l = 0; l < NLAYER; ++l) {
        const float* xin = (l == 0) ? x : out;

        // in_proj: [1024,1024] x [4096,1024]^T -> xz  (128x128 tiles, 256 blocks, 32 iters)
        gemm128<32><<<dim3(4096 / 128, L / 128, 1), 256, 0, stream>>>(
            xn_bf, D, in_w + (size_t)l * 4096 * 1024, D, 4096, xz, 4096, 0);

        conv_silu_kernel<<<L * DI / 256, 256, 0, stream>>>(
            xz, conv_w + (size_t)l * DI * KCONV, conv_b + (size_t)l * DI, u_bf);

        // x_proj split-K=8: [1024,2048] x [96,2048]^T -> part[s][1024][96]  (8 iters each)
        gemm_pipe<0, 8><<<dim3(2, L / 128, KSPLIT), 256, 0, stream>>>(
            u_bf, DI, xproj_w + (size_t)l * 96 * 2048, DI, 96,
            part, XD, XD, (long)L * XD, nullptr);
        xred_kernel<<<(L * XD) / 256, 256, 0, stream>>>(part, xdbl_bf, xdblBC);

        // dt_proj: [1024,64] x [2048,64]^T -> delta, softplus(+bias)  (2 iters)
        gemm_pipe<1, 2><<<dim3(2048 / 64, L / 128, 1), 256, 0, stream>>>(
            xdbl_bf, DTR, dt_w + (size_t)l * 2048 * 64, DTR, 2048,
            delta, DI, DI, 0, dt_b + (size_t)l * DI);

        // selective scan: single dispatch, no cross-block deps (replaces scanA/B/C)
        scan1_kernel<<<DI / SCAND, 256, 0, stream>>>(
            delta, u_bf, xdblBC, A_log + (size_t)l * DI * NSTATE, xz,
            D_skip + (size_t)l * DI, yg_bf);

        // out_proj split-K=4: [1024,2048] x [1024,2048]^T -> part2  (16 iters each)
        gemm128<2048 / (OSPLIT * BK)><<<dim3(1024 / 128, L / 128, OSPLIT), 256, 0, stream>>>(
            yg_bf, DI, out_w + (size_t)l * 1024 * 2048, DI, 1024,
            part2, D, (long)L * D);

        // reduce + residual (+RMSNorm input for next layer)
        if (l < NLAYER - 1)
            reduce_kernel<OSPLIT, true><<<L, 256, 0, stream>>>(
                part2, xin, norm_w + (size_t)(l + 1) * D, out, xn_bf);
        else
            reduce_kernel<OSPLIT, false><<<L, 256, 0, stream>>>(
                part2, xin, nullptr, out, nullptr);
    }
}